// Round 4
// baseline (111.430 us; speedup 1.0000x reference)
//
#include <hip/hip_runtime.h>

#define C     32                  // elements per lane (h and x each)
#define WV    4                   // waves per block (adjacent windows)
#define WIN   (WV * 64 * C)       // 8192 block window
#define VALID (WIN - 1024)        // 7168 valid outputs per block
#define HALON 512

__device__ __forceinline__ float fast_tanh(float y) {
    // tanh(y) = 1 - 2/(exp(2y)+1);  exp(2y) = exp2(y * 2*log2(e))
    float e = __builtin_amdgcn_exp2f(y * 2.885390081777927f);
    float r = __builtin_amdgcn_rcpf(e + 1.0f);
    return fmaf(-2.0f, r, 1.0f);  // saturates correctly at +/-inf
}

// One layer: h[j] = wh0*h[j] + wh1*h[j+D];  x[j] = tanh(h_new[j] + wx0*x[j] + wx1*x[j+D])
// Window element j+D beyond the lane chunk: lane+1 (D<C) or lane+D/C (D>=C) via shfl;
// beyond the WAVE window: next wave's published head in LDS. Wave 3 wraps to halo[0]
// (bounded garbage, lands only in the invalid block-halo tail).
template<int D>
__device__ __forceinline__ void layer(float (&h)[C], float (&x)[C],
        float wh0, float wh1, float wx0, float wx1, int lane, int wv,
        float (&haloH)[WV][HALON], float (&haloX)[WV][HALON])
{
    const int nw = (wv + 1) & (WV - 1);

    // ---- publish OLD head (first D elements of this wave's window) ----
    if constexpr (D < C) {
        if (lane == 0) {
            #pragma unroll
            for (int j = 0; j < D; ++j) { haloH[wv][j] = h[j]; haloX[wv][j] = x[j]; }
        }
    } else {
        constexpr int M = D / C;       // 1,2,4,8,16
        if (lane < M) {
            #pragma unroll
            for (int q = 0; q < C / 4; ++q) {
                *(float4*)&haloH[wv][lane * C + q * 4] =
                    make_float4(h[q*4+0], h[q*4+1], h[q*4+2], h[q*4+3]);
                *(float4*)&haloX[wv][lane * C + q * 4] =
                    make_float4(x[q*4+0], x[q*4+1], x[q*4+2], x[q*4+3]);
            }
        }
    }
    __syncthreads();                   // heads visible

    if constexpr (D < C) {
        // prefetch the D cross-boundary old values (SSA: values read here are old)
        float th[D], tx[D];
        #pragma unroll
        for (int j = 0; j < D; ++j) {
            th[j] = __shfl(h[j], (lane + 1) & 63, 64);
            tx[j] = __shfl(x[j], (lane + 1) & 63, 64);
            if (lane == 63) { th[j] = haloH[nw][j]; tx[j] = haloX[nw][j]; }
        }
        #pragma unroll
        for (int j = 0; j < C; ++j) {  // ascending: h[j+D]/x[j+D] still old
            float hd = (j + D < C) ? h[j + D] : th[j + D - C];
            float xd = (j + D < C) ? x[j + D] : tx[j + D - C];
            float hn = fmaf(wh0, h[j], wh1 * hd);
            float s  = fmaf(wx0, x[j], hn);
            s        = fmaf(wx1, xd, s);
            h[j] = hn;
            x[j] = fast_tanh(s);
        }
    } else {
        constexpr int M = D / C;
        #pragma unroll
        for (int j = 0; j < C; ++j) {
            float hd = __shfl(h[j], (lane + M) & 63, 64);  // old: shfl precedes write
            float xd = __shfl(x[j], (lane + M) & 63, 64);
            if (lane >= 64 - M) {      // chunk lives in next wave -> LDS halo
                hd = haloH[nw][(lane + M - 64) * C + j];
                xd = haloX[nw][(lane + M - 64) * C + j];
            }
            float hn = fmaf(wh0, h[j], wh1 * hd);
            float s  = fmaf(wx0, x[j], hn);
            s        = fmaf(wx1, xd, s);
            h[j] = hn;
            x[j] = fast_tanh(s);
        }
    }
    __syncthreads();                   // halo reads done before next layer's publish
}

__global__ __launch_bounds__(WV * 64, 4) void rawstack_coop(
    const float* __restrict__ hin, const float* __restrict__ xin,
    const float* __restrict__ wh,  const float* __restrict__ wx,
    float* __restrict__ out, int T, int Lout)
{
    __shared__ float haloH[WV][HALON];
    __shared__ float haloX[WV][HALON];

    const int lane = threadIdx.x & 63;
    const int wv   = threadIdx.x >> 6;
    const int b    = blockIdx.y;
    const int W    = blockIdx.x * VALID;   // block window start in the row

    const float* hb = hin + (size_t)b * T;
    const float* xb = xin + (size_t)b * T;

    // ---- load this lane's chunk: 8 float4 per array, clamped at row end ----
    float h[C], x[C];
    const int cbase = W + wv * (64 * C) + lane * C;
    #pragma unroll
    for (int q = 0; q < C / 4; ++q) {
        int e = cbase + q * 4;
        e = (e > T - 4) ? (T - 4) : e;     // only positions >= T get garbage
        float4 hv = *(const float4*)(hb + e);
        float4 xv = *(const float4*)(xb + e);
        h[q*4+0] = hv.x; h[q*4+1] = hv.y; h[q*4+2] = hv.z; h[q*4+3] = hv.w;
        x[q*4+0] = xv.x; x[q*4+1] = xv.y; x[q*4+2] = xv.z; x[q*4+3] = xv.w;
    }

    // ---- 10 layers ----
    layer<  1>(h, x, wh[ 0], wh[ 1], wx[ 0], wx[ 1], lane, wv, haloH, haloX);
    layer<  2>(h, x, wh[ 2], wh[ 3], wx[ 2], wx[ 3], lane, wv, haloH, haloX);
    layer<  4>(h, x, wh[ 4], wh[ 5], wx[ 4], wx[ 5], lane, wv, haloH, haloX);
    layer<  8>(h, x, wh[ 6], wh[ 7], wx[ 6], wx[ 7], lane, wv, haloH, haloX);
    layer< 16>(h, x, wh[ 8], wh[ 9], wx[ 8], wx[ 9], lane, wv, haloH, haloX);
    layer< 32>(h, x, wh[10], wh[11], wx[10], wx[11], lane, wv, haloH, haloX);
    layer< 64>(h, x, wh[12], wh[13], wx[12], wx[13], lane, wv, haloH, haloX);
    layer<128>(h, x, wh[14], wh[15], wx[14], wx[15], lane, wv, haloH, haloX);
    layer<256>(h, x, wh[16], wh[17], wx[16], wx[17], lane, wv, haloH, haloX);
    layer<512>(h, x, wh[18], wh[19], wx[18], wx[19], lane, wv, haloH, haloX);

    // ---- store valid outputs (rows misaligned for float4 -> scalar stores) ----
    float* ob = out + (size_t)b * Lout;
    const int base = wv * (64 * C) + lane * C;
    #pragma unroll
    for (int j = 0; j < C; ++j) {
        const int idx = base + j;
        const int col = W + idx;
        if (idx < VALID && col < Lout) ob[col] = x[j];
    }
}

extern "C" void kernel_launch(void* const* d_in, const int* in_sizes, int n_in,
                              void* d_out, int out_size, void* d_ws, size_t ws_size,
                              hipStream_t stream) {
    const float* h  = (const float*)d_in[0];
    const float* x  = (const float*)d_in[1];
    const float* wh = (const float*)d_in[2];
    const float* wx = (const float*)d_in[3];
    float* out = (float*)d_out;

    const int B    = 64;
    const int T    = in_sizes[0] / B;   // 131072
    const int Lout = out_size / B;      // 130049

    const int blocksPerRow = (Lout + VALID - 1) / VALID;   // 19

    dim3 grid(blocksPerRow, B);
    rawstack_coop<<<grid, WV * 64, 0, stream>>>(h, x, wh, wx, out, T, Lout);
}

// Round 5
// 84.747 us; speedup vs baseline: 1.3149x; 1.3149x over previous
//
#include <hip/hip_runtime.h>

#define C     32                  // elements per lane (h and x each)
#define WV    4                   // waves per block (adjacent windows)
#define WIN   (WV * 64 * C)       // 8192 block window
#define VALID (WIN - 1024)        // 7168 valid outputs per block
#define RSTR  36                  // padded chunk-halo row stride (floats): 16B-aligned, conflict<=2-way
#define HSZ   (16 * RSTR)         // 16 rows max (M=16 for D=512)

__device__ __forceinline__ float fast_tanh(float y) {
    // tanh(y) = 1 - 2/(exp(2y)+1);  exp(2y) = exp2(y * 2*log2(e))
    float e = __builtin_amdgcn_exp2f(y * 2.885390081777927f);
    float r = __builtin_amdgcn_rcpf(e + 1.0f);
    return fmaf(-2.0f, r, 1.0f);  // saturates correctly at +/-inf
}

// One layer: h[j] = wh0*h[j] + wh1*h[j+D];  x[j] = tanh(h_new[j] + wx0*x[j] + wx1*x[j+D])
// j+D beyond lane chunk: lane+1 (D<C) or lane+M (D=M*C) via shfl; beyond the wave:
// next wave's published head in LDS (wave 3 wraps to wave 0 -> bounded garbage that
// provably lands only in the invalid block-halo tail, telescoping with the layers).
// Halo is double-buffered by layer parity -> single barrier per layer.
template<int D, int PAR>
__device__ __forceinline__ void layer(float (&h)[C], float (&x)[C],
        float wh0, float wh1, float wx0, float wx1, int lane, int wv,
        float (*haloH)[WV][HSZ], float (*haloX)[WV][HSZ])
{
    const int nw = (wv + 1) & (WV - 1);

    // ---- publish OLD data needed by the previous wave into buffer PAR ----
    if constexpr (D < C) {
        if (lane == 0) {
            #pragma unroll
            for (int j = 0; j < D; ++j) {
                haloH[PAR][wv][j] = h[j];
                haloX[PAR][wv][j] = x[j];
            }
        }
    } else {
        constexpr int M = D / C;       // 1,2,4,8,16
        if (lane < M) {
            #pragma unroll
            for (int q = 0; q < C / 4; ++q) {
                *(float4*)&haloH[PAR][wv][lane * RSTR + q * 4] =
                    make_float4(h[q*4+0], h[q*4+1], h[q*4+2], h[q*4+3]);
                *(float4*)&haloX[PAR][wv][lane * RSTR + q * 4] =
                    make_float4(x[q*4+0], x[q*4+1], x[q*4+2], x[q*4+3]);
            }
        }
    }
    __syncthreads();                   // buffer PAR ready; PAR^1 no longer read

    if constexpr (D < C) {
        // prefetch the D cross-boundary old values (lockstep-safe: reads precede writes)
        float th[D], tx[D];
        #pragma unroll
        for (int j = 0; j < D; ++j) {
            th[j] = __shfl(h[j], (lane + 1) & 63, 64);
            tx[j] = __shfl(x[j], (lane + 1) & 63, 64);
            if (lane == 63) { th[j] = haloH[PAR][nw][j]; tx[j] = haloX[PAR][nw][j]; }
        }
        #pragma unroll
        for (int j = 0; j < C; ++j) {  // ascending: local h[j+D]/x[j+D] still old
            float hd = (j + D < C) ? h[j + D] : th[j + D - C];
            float xd = (j + D < C) ? x[j + D] : tx[j + D - C];
            float hn = fmaf(wh0, h[j], wh1 * hd);
            float s  = fmaf(wx0, x[j], hn);
            s        = fmaf(wx1, xd, s);
            h[j] = hn;
            x[j] = fast_tanh(s);
        }
    } else {
        constexpr int M = D / C;
        #pragma unroll
        for (int j = 0; j < C; ++j) {
            float hd = __shfl(h[j], (lane + M) & 63, 64);  // old: shfl precedes write
            float xd = __shfl(x[j], (lane + M) & 63, 64);
            if (lane >= 64 - M) {      // chunk lives in next wave -> LDS halo
                hd = haloH[PAR][nw][(lane + M - 64) * RSTR + j];
                xd = haloX[PAR][nw][(lane + M - 64) * RSTR + j];
            }
            float hn = fmaf(wh0, h[j], wh1 * hd);
            float s  = fmaf(wx0, x[j], hn);
            s        = fmaf(wx1, xd, s);
            h[j] = hn;
            x[j] = fast_tanh(s);
        }
    }
    // no trailing barrier: next layer writes buffer PAR^1; re-use of PAR is fenced
    // by the NEXT layer's barrier (every wave must pass it before anyone reaches PAR again)
}

__global__ __launch_bounds__(WV * 64, 2) void rawstack_coop(
    const float* __restrict__ hin, const float* __restrict__ xin,
    const float* __restrict__ wh,  const float* __restrict__ wx,
    float* __restrict__ out, int T, int Lout)
{
    __shared__ float haloH[2][WV][HSZ];
    __shared__ float haloX[2][WV][HSZ];

    const int lane = threadIdx.x & 63;
    const int wv   = threadIdx.x >> 6;
    const int b    = blockIdx.y;
    const int W    = blockIdx.x * VALID;   // block window start in the row

    const float* hb = hin + (size_t)b * T;
    const float* xb = xin + (size_t)b * T;

    // ---- load this lane's chunk: 8 float4 per array, clamped at row end ----
    float h[C], x[C];
    const int cbase = W + wv * (64 * C) + lane * C;
    #pragma unroll
    for (int q = 0; q < C / 4; ++q) {
        int e = cbase + q * 4;
        e = (e > T - 4) ? (T - 4) : e;     // only positions >= T get garbage
        float4 hv = *(const float4*)(hb + e);
        float4 xv = *(const float4*)(xb + e);
        h[q*4+0] = hv.x; h[q*4+1] = hv.y; h[q*4+2] = hv.z; h[q*4+3] = hv.w;
        x[q*4+0] = xv.x; x[q*4+1] = xv.y; x[q*4+2] = xv.z; x[q*4+3] = xv.w;
    }

    // ---- 10 layers, alternating halo parity ----
    layer<  1,0>(h, x, wh[ 0], wh[ 1], wx[ 0], wx[ 1], lane, wv, haloH, haloX);
    layer<  2,1>(h, x, wh[ 2], wh[ 3], wx[ 2], wx[ 3], lane, wv, haloH, haloX);
    layer<  4,0>(h, x, wh[ 4], wh[ 5], wx[ 4], wx[ 5], lane, wv, haloH, haloX);
    layer<  8,1>(h, x, wh[ 6], wh[ 7], wx[ 6], wx[ 7], lane, wv, haloH, haloX);
    layer< 16,0>(h, x, wh[ 8], wh[ 9], wx[ 8], wx[ 9], lane, wv, haloH, haloX);
    layer< 32,1>(h, x, wh[10], wh[11], wx[10], wx[11], lane, wv, haloH, haloX);
    layer< 64,0>(h, x, wh[12], wh[13], wx[12], wx[13], lane, wv, haloH, haloX);
    layer<128,1>(h, x, wh[14], wh[15], wx[14], wx[15], lane, wv, haloH, haloX);
    layer<256,0>(h, x, wh[16], wh[17], wx[16], wx[17], lane, wv, haloH, haloX);
    layer<512,1>(h, x, wh[18], wh[19], wx[18], wx[19], lane, wv, haloH, haloX);

    // ---- store valid outputs ----
    float* ob = out + (size_t)b * Lout;
    const int base = wv * (64 * C) + lane * C;
    #pragma unroll
    for (int j = 0; j < C; ++j) {
        const int idx = base + j;
        const int col = W + idx;
        if (idx < VALID && col < Lout) ob[col] = x[j];
    }
}

extern "C" void kernel_launch(void* const* d_in, const int* in_sizes, int n_in,
                              void* d_out, int out_size, void* d_ws, size_t ws_size,
                              hipStream_t stream) {
    const float* h  = (const float*)d_in[0];
    const float* x  = (const float*)d_in[1];
    const float* wh = (const float*)d_in[2];
    const float* wx = (const float*)d_in[3];
    float* out = (float*)d_out;

    const int B    = 64;
    const int T    = in_sizes[0] / B;   // 131072
    const int Lout = out_size / B;      // 130049

    const int blocksPerRow = (Lout + VALID - 1) / VALID;   // 19

    dim3 grid(blocksPerRow, B);
    rawstack_coop<<<grid, WV * 64, 0, stream>>>(h, x, wh, wx, out, T, Lout);
}

// Round 6
// 61.640 us; speedup vs baseline: 1.8078x; 1.3749x over previous
//
#include <hip/hip_runtime.h>

#define WV    4
#define NT    (WV * 64)            // 256 threads per block
#define C     16                   // floats per thread per array (h and x)
#define WIN   (NT * C)             // 4096-float block window
#define VALID (WIN - 1024)         // 3072 valid outputs per block
#define NQ    (C / 4)              // 4 quads per array per thread

// XOR-swizzle: spreads stride-16 chunk accesses across bank groups while
// preserving float4 contiguity/alignment (XOR touches word-bits 2..4 only,
// key taken from bits 5..7 so all 4 words of a quad move together).
__device__ __forceinline__ int swz(int w) {
    return w ^ (((w >> 5) & 7) << 2);
}

__device__ __forceinline__ float fast_tanh(float y) {
    // tanh(y) = 1 - 2/(exp(2y)+1); exp via exp2. Saturates correctly at +/-inf.
    float e = __builtin_amdgcn_exp2f(y * 2.885390081777927f);
    float r = __builtin_amdgcn_rcpf(e + 1.0f);
    return fmaf(-2.0f, r, 1.0f);
}

__device__ __forceinline__ void publish(float* sh, float* sx, int t,
                                        const float (&h)[C], const float (&x)[C]) {
    #pragma unroll
    for (int q = 0; q < NQ; ++q) {
        const int p = swz(t * C + q * 4);
        *(float4*)&sh[p] = make_float4(h[q*4+0], h[q*4+1], h[q*4+2], h[q*4+3]);
        *(float4*)&sx[p] = make_float4(x[q*4+0], x[q*4+1], x[q*4+2], x[q*4+3]);
    }
}

// D = 1 or 2: tail D values come from the next thread's head quad in LDS.
template<int D>
__device__ __forceinline__ void layer_small(float* sh, float* sx, int t,
        float (&h)[C], float (&x)[C], float wh0, float wh1, float wx0, float wx1) {
    const int p = swz(min((t + 1) * C, WIN - 4));   // t=255 clamps into garbage-safe tail
    const float4 th = *(const float4*)&sh[p];
    const float4 tx = *(const float4*)&sx[p];
    __syncthreads();                    // all reads of old window done before writes
    const float tha[4] = {th.x, th.y, th.z, th.w};
    const float txa[4] = {tx.x, tx.y, tx.z, tx.w};
    #pragma unroll
    for (int j = 0; j < C; ++j) {       // ascending j: h[j+D]/x[j+D] still old
        float hd = (j + D < C) ? h[j + D] : tha[j + D - C];
        float xd = (j + D < C) ? x[j + D] : txa[j + D - C];
        float hn = fmaf(wh0, h[j], wh1 * hd);
        float s  = fmaf(wx0, x[j], hn);
        s        = fmaf(wx1, xd, s);
        h[j] = hn;
        x[j] = fast_tanh(s);
    }
    publish(sh, sx, t, h, x);
    __syncthreads();
}

// D multiple of 4 (4..512), runtime: +D neighbors via aligned float4 LDS reads.
__device__ __forceinline__ void layer_big(float* sh, float* sx, int t, int D,
        float (&h)[C], float (&x)[C], float wh0, float wh1, float wx0, float wx1) {
    float nh[C], nx[C];
    #pragma unroll
    for (int q = 0; q < NQ; ++q) {
        const int p = swz(min(t * C + D + q * 4, WIN - 4));  // clamp only hits garbage tail
        const float4 a = *(const float4*)&sh[p];
        const float4 b = *(const float4*)&sx[p];
        nh[q*4+0] = a.x; nh[q*4+1] = a.y; nh[q*4+2] = a.z; nh[q*4+3] = a.w;
        nx[q*4+0] = b.x; nx[q*4+1] = b.y; nx[q*4+2] = b.z; nx[q*4+3] = b.w;
    }
    __syncthreads();                    // reads done before anyone overwrites
    #pragma unroll
    for (int j = 0; j < C; ++j) {
        float hn = fmaf(wh0, h[j], wh1 * nh[j]);
        float s  = fmaf(wx0, x[j], hn);
        s        = fmaf(wx1, nx[j], s);
        h[j] = hn;
        x[j] = fast_tanh(s);
    }
    publish(sh, sx, t, h, x);
    __syncthreads();
}

__global__ __launch_bounds__(NT, 2) void rawstack_lds(
    const float* __restrict__ hin, const float* __restrict__ xin,
    const float* __restrict__ wh,  const float* __restrict__ wx,
    float* __restrict__ out, int T, int Lout)
{
    __shared__ __align__(16) float sh[WIN];
    __shared__ __align__(16) float sx[WIN];

    const int t = threadIdx.x;
    const int b = blockIdx.y;
    const int W = blockIdx.x * VALID;   // block window start (always < Lout)

    const float* hb = hin + (size_t)b * T;
    const float* xb = xin + (size_t)b * T;

    // ---- load this thread's chunk (clamped at row end; garbage stays in invalid tail) ----
    float h[C], x[C];
    #pragma unroll
    for (int q = 0; q < NQ; ++q) {
        int e = W + t * C + q * 4;
        e = (e > T - 4) ? (T - 4) : e;
        const float4 hv = *(const float4*)(hb + e);
        const float4 xv = *(const float4*)(xb + e);
        h[q*4+0] = hv.x; h[q*4+1] = hv.y; h[q*4+2] = hv.z; h[q*4+3] = hv.w;
        x[q*4+0] = xv.x; x[q*4+1] = xv.y; x[q*4+2] = xv.z; x[q*4+3] = xv.w;
    }
    publish(sh, sx, t, h, x);
    __syncthreads();

    // ---- layers 0,1 (D=1,2): templated; layers 2..9 (D=4..512): ONE looped body ----
    layer_small<1>(sh, sx, t, h, x, wh[0], wh[1], wx[0], wx[1]);
    layer_small<2>(sh, sx, t, h, x, wh[2], wh[3], wx[2], wx[3]);
    #pragma unroll 1
    for (int i = 2; i < 10; ++i) {
        layer_big(sh, sx, t, 1 << i, h, x,
                  wh[2*i], wh[2*i+1], wx[2*i], wx[2*i+1]);
    }

    // ---- store valid outputs from registers ----
    float* ob = out + (size_t)b * Lout;
    #pragma unroll
    for (int j = 0; j < C; ++j) {
        const int idx = t * C + j;
        const int col = W + idx;
        if (idx < VALID && col < Lout) ob[col] = x[j];
    }
}

extern "C" void kernel_launch(void* const* d_in, const int* in_sizes, int n_in,
                              void* d_out, int out_size, void* d_ws, size_t ws_size,
                              hipStream_t stream) {
    const float* h  = (const float*)d_in[0];
    const float* x  = (const float*)d_in[1];
    const float* wh = (const float*)d_in[2];
    const float* wx = (const float*)d_in[3];
    float* out = (float*)d_out;

    const int B    = 64;
    const int T    = in_sizes[0] / B;   // 131072
    const int Lout = out_size / B;      // 130049

    const int blocksPerRow = (Lout + VALID - 1) / VALID;   // 43

    dim3 grid(blocksPerRow, B);
    rawstack_lds<<<grid, NT, 0, stream>>>(h, x, wh, wx, out, T, Lout);
}

// Round 7
// 51.004 us; speedup vs baseline: 2.1847x; 1.2085x over previous
//
#include <hip/hip_runtime.h>

#define NT    256
#define NWV   4
#define WIN   4096               // block window (floats)
#define VALID 3072               // valid outputs per block
#define C     16                 // elements per lane per array
#define TBX   4096               // tb word offset of the x-array half

// Transpose-buffer swizzle: XOR word bits 2..4 with bits 5..7.
// Keeps float4 groups contiguous/aligned; write pattern (16l+4q) -> 4-way
// conflict (1.58x, acceptable); read pattern (l+64k) -> 2-way (free).
__device__ __forceinline__ int tswz(int w) { return w ^ (((w >> 5) & 7) << 2); }

__device__ __forceinline__ float fast_tanh(float y) {
    // tanh(y) = 1 - 2/(exp(2y)+1); exp via exp2. Saturates correctly at +/-inf.
    float e = __builtin_amdgcn_exp2f(y * 2.885390081777927f);
    float r = __builtin_amdgcn_rcpf(e + 1.0f);
    return fmaf(-2.0f, r, 1.0f);
}

// ---------------- Phase A: contiguous layout, D in {1,2,4,8} ----------------
// Lane owns elements [w0+16*lane, +16). Tail j+D>=16 comes from lane+1 via
// shuffle; lane 63 instead reads the next wave's published head from hA.
// Wave 3 wraps to wave 0 -> garbage lands only in the invalid block tail.
template<int D, int I>
__device__ __forceinline__ void layerA(float (&h)[C], float (&x)[C],
        const float* wh, const float* wx, int lane, int wv,
        float (*hA)[NWV][2][8])
{
    const float wh0 = wh[2*I], wh1 = wh[2*I+1];
    const float wx0 = wx[2*I], wx1 = wx[2*I+1];
    const int nw = (wv + 1) & (NWV - 1);

    if (lane == 0) {
        #pragma unroll
        for (int j = 0; j < D; ++j) { hA[I][wv][0][j] = h[j]; hA[I][wv][1][j] = x[j]; }
    }
    __syncthreads();

    float th[D], tx[D];
    #pragma unroll
    for (int j = 0; j < D; ++j) {
        th[j] = __shfl(h[j], (lane + 1) & 63, 64);
        tx[j] = __shfl(x[j], (lane + 1) & 63, 64);
        if (lane == 63) { th[j] = hA[I][nw][0][j]; tx[j] = hA[I][nw][1][j]; }
    }
    #pragma unroll
    for (int j = 0; j < C; ++j) {           // ascending j: h[j+D]/x[j+D] still old
        float hd = (j + D < C) ? h[j + D] : th[j + D - C];
        float xd = (j + D < C) ? x[j + D] : tx[j + D - C];
        float hn = fmaf(wh0, h[j], wh1 * hd);
        float s  = fmaf(wx0, x[j], hn);
        s        = fmaf(wx1, xd, s);
        h[j] = hn;
        x[j] = fast_tanh(s);
    }
}

// ------------- Phase B: stride-64 interleave, slot k = element lane+64k -------------
// Halo overlay inside the publisher's own tb quarter, parity P (WAR-safe with
// one barrier per layer). haloWord(wv,P,arr,s,lane) = wv*1024 + P*512 + ... wait:
// per-array regions: h at [wv*1024 + P*512 + s*64 + l], x at TBX + same.
__device__ __forceinline__ int haloW(int wv, int P, int s, int l) {
    return wv * 1024 + P * 512 + s * 64 + l;
}

// D = R (16 or 32): j+R -> lane (l+R)&63, slot k (+1 for high lanes).
template<int R, int P, int I>
__device__ __forceinline__ void layerBR(float (&hh)[C], float (&xx)[C],
        const float* wh, const float* wx, int lane, int wv, float* tb)
{
    const float wh0 = wh[2*I], wh1 = wh[2*I+1];
    const float wx0 = wx[2*I], wx1 = wx[2*I+1];
    const int nw = (wv + 1) & (NWV - 1);

    tb[haloW(wv, P, 0, lane)]       = hh[0];   // publish slot 0 (all lanes)
    tb[TBX + haloW(wv, P, 0, lane)] = xx[0];
    __syncthreads();

    float fh[C + 1], fx[C + 1];
    #pragma unroll
    for (int k = 0; k < C; ++k) {
        fh[k] = __shfl(hh[k], (lane + R) & 63, 64);
        fx[k] = __shfl(xx[k], (lane + R) & 63, 64);
    }
    fh[C] = 0.0f; fx[C] = 0.0f;
    if (lane >= 64 - R) {                    // slot-16 = next wave's slot 0
        fh[C] = tb[haloW(nw, P, 0, lane - (64 - R))];
        fx[C] = tb[TBX + haloW(nw, P, 0, lane - (64 - R))];
    }
    const bool lo = lane < 64 - R;
    #pragma unroll
    for (int k = 0; k < C; ++k) {
        float hd = lo ? fh[k] : fh[k + 1];
        float xd = lo ? fx[k] : fx[k + 1];
        float hn = fmaf(wh0, hh[k], wh1 * hd);
        float s  = fmaf(wx0, xx[k], hn);
        s        = fmaf(wx1, xd, s);
        hh[k] = hn;
        xx[k] = fast_tanh(s);
    }
}

// D = 64*M (M in {1,2,4,8}): pure slot shift; only slots >= 16-M cross the wave.
template<int M, int P, int I>
__device__ __forceinline__ void layerBM(float (&hh)[C], float (&xx)[C],
        const float* wh, const float* wx, int lane, int wv, float* tb)
{
    const float wh0 = wh[2*I], wh1 = wh[2*I+1];
    const float wx0 = wx[2*I], wx1 = wx[2*I+1];
    const int nw = (wv + 1) & (NWV - 1);

    #pragma unroll
    for (int s = 0; s < M; ++s) {            // publish head slots
        tb[haloW(wv, P, s, lane)]       = hh[s];
        tb[TBX + haloW(wv, P, s, lane)] = xx[s];
    }
    __syncthreads();

    float nh[M], nx[M];
    #pragma unroll
    for (int s = 0; s < M; ++s) {            // next wave's head slots
        nh[s] = tb[haloW(nw, P, s, lane)];
        nx[s] = tb[TBX + haloW(nw, P, s, lane)];
    }
    #pragma unroll
    for (int k = 0; k < C; ++k) {            // ascending k: hh[k+M] still old
        float hd = (k + M < C) ? hh[k + M] : nh[k + M - C];
        float xd = (k + M < C) ? xx[k + M] : nx[k + M - C];
        float hn = fmaf(wh0, hh[k], wh1 * hd);
        float s  = fmaf(wx0, xx[k], hn);
        s        = fmaf(wx1, xd, s);
        hh[k] = hn;
        xx[k] = fast_tanh(s);
    }
}

__global__ __launch_bounds__(NT, 2) void rawstack_ilv(
    const float* __restrict__ hin, const float* __restrict__ xin,
    const float* __restrict__ wh,  const float* __restrict__ wx,
    float* __restrict__ out, int T, int Lout)
{
    __shared__ __align__(16) float tb[2 * 4096];      // 32 KB: transpose, then halos
    __shared__ float hA[4][NWV][2][8];                // 1 KB phase-A head halos

    const int lane = threadIdx.x & 63;
    const int wv   = threadIdx.x >> 6;
    const int b    = blockIdx.y;
    const int W    = blockIdx.x * VALID;

    const float* hb = hin + (size_t)b * T;
    const float* xb = xin + (size_t)b * T;

    // ---- load contiguous chunks (clamped; garbage stays in invalid tail) ----
    float h[C], x[C];
    #pragma unroll
    for (int q = 0; q < C / 4; ++q) {
        int e = W + wv * 1024 + lane * C + q * 4;
        e = (e > T - 4) ? (T - 4) : e;
        const float4 hv = *(const float4*)(hb + e);
        const float4 xv = *(const float4*)(xb + e);
        h[q*4+0] = hv.x; h[q*4+1] = hv.y; h[q*4+2] = hv.z; h[q*4+3] = hv.w;
        x[q*4+0] = xv.x; x[q*4+1] = xv.y; x[q*4+2] = xv.z; x[q*4+3] = xv.w;
    }

    // ---- phase A: D = 1,2,4,8 ----
    layerA<1, 0>(h, x, wh, wx, lane, wv, hA);
    layerA<2, 1>(h, x, wh, wx, lane, wv, hA);
    layerA<4, 2>(h, x, wh, wx, lane, wv, hA);
    layerA<8, 3>(h, x, wh, wx, lane, wv, hA);

    // ---- transpose to within-wave stride-64 interleave (wave-local) ----
    #pragma unroll
    for (int q = 0; q < C / 4; ++q) {
        const int wH = tswz(wv * 1024 + lane * C + q * 4);
        *(float4*)&tb[wH]       = make_float4(h[q*4+0], h[q*4+1], h[q*4+2], h[q*4+3]);
        *(float4*)&tb[TBX + wH] = make_float4(x[q*4+0], x[q*4+1], x[q*4+2], x[q*4+3]);
    }
    __syncthreads();
    float hh[C], xx[C];
    #pragma unroll
    for (int k = 0; k < C; ++k) {
        const int wR = tswz(wv * 1024 + lane + 64 * k);
        hh[k] = tb[wR];
        xx[k] = tb[TBX + wR];
    }

    // ---- phase B: D = 16,32 (shuffle+select), D = 64..512 (slot shift) ----
    layerBR<16, 0, 4>(hh, xx, wh, wx, lane, wv, tb);
    layerBR<32, 1, 5>(hh, xx, wh, wx, lane, wv, tb);
    layerBM< 1, 0, 6>(hh, xx, wh, wx, lane, wv, tb);   // D=64
    layerBM< 2, 1, 7>(hh, xx, wh, wx, lane, wv, tb);   // D=128
    layerBM< 4, 0, 8>(hh, xx, wh, wx, lane, wv, tb);   // D=256
    layerBM< 8, 1, 9>(hh, xx, wh, wx, lane, wv, tb);   // D=512

    // ---- store (interleaved layout; waves 0..2 hold the 3072 valid outputs) ----
    if (wv < 3) {
        float* ob = out + (size_t)b * Lout;
        const int base = W + wv * 1024 + lane;
        #pragma unroll
        for (int k = 0; k < C; ++k) {
            const int col = base + 64 * k;
            if (col < Lout) ob[col] = xx[k];
        }
    }
}

extern "C" void kernel_launch(void* const* d_in, const int* in_sizes, int n_in,
                              void* d_out, int out_size, void* d_ws, size_t ws_size,
                              hipStream_t stream) {
    const float* h  = (const float*)d_in[0];
    const float* x  = (const float*)d_in[1];
    const float* wh = (const float*)d_in[2];
    const float* wx = (const float*)d_in[3];
    float* out = (float*)d_out;

    const int B    = 64;
    const int T    = in_sizes[0] / B;   // 131072
    const int Lout = out_size / B;      // 130049

    const int blocksPerRow = (Lout + VALID - 1) / VALID;   // 43

    dim3 grid(blocksPerRow, B);
    rawstack_ilv<<<grid, NT, 0, stream>>>(h, x, wh, wx, out, T, Lout);
}

// Round 8
// 50.501 us; speedup vs baseline: 2.2065x; 1.0100x over previous
//
#include <hip/hip_runtime.h>

#define NT    256
#define NWV   4
#define WIN   4096               // block window (floats)
#define VALID 3072               // valid outputs per block
#define C     16                 // elements per lane per array

// tb: 4096 floats (16 KB), triple-purposed:
//   transpose buffer (h then x, sequentially), per-wave quarter [wv*1024,+1024)
//   phase-B halos: P0=[0,2048) for R16/M1/M4, P1=[2048,3072) for R32/M2,
//   M8 uses [0,4096) after an extra barrier.
#define P0B 0
#define P1B 2048

// XOR-swizzle for the transpose pattern: word bits 2..4 ^= bits 5..7.
// Keeps float4 groups contiguous/aligned; measured 0 conflicts in R7.
__device__ __forceinline__ int tswz(int w) { return w ^ (((w >> 5) & 7) << 2); }

__device__ __forceinline__ float fast_tanh(float y) {
    // tanh(y) = 1 - 2/(exp(2y)+1); exp via exp2. Saturates correctly at +/-inf.
    float e = __builtin_amdgcn_exp2f(y * 2.885390081777927f);
    float r = __builtin_amdgcn_rcpf(e + 1.0f);
    return fmaf(-2.0f, r, 1.0f);
}

// ---------------- Phase A: contiguous layout, D in {1,2,4,8} ----------------
template<int D, int I>
__device__ __forceinline__ void layerA(float (&h)[C], float (&x)[C],
        const float* wh, const float* wx, int lane, int wv,
        float (*hA)[NWV][2][8])
{
    const float wh0 = wh[2*I], wh1 = wh[2*I+1];
    const float wx0 = wx[2*I], wx1 = wx[2*I+1];
    const int nw = (wv + 1) & (NWV - 1);

    if (lane == 0) {
        #pragma unroll
        for (int j = 0; j < D; ++j) { hA[I][wv][0][j] = h[j]; hA[I][wv][1][j] = x[j]; }
    }
    __syncthreads();

    float th[D], tx[D];
    #pragma unroll
    for (int j = 0; j < D; ++j) {
        th[j] = __shfl(h[j], (lane + 1) & 63, 64);
        tx[j] = __shfl(x[j], (lane + 1) & 63, 64);
        if (lane == 63) { th[j] = hA[I][nw][0][j]; tx[j] = hA[I][nw][1][j]; }
    }
    #pragma unroll
    for (int j = 0; j < C; ++j) {           // ascending j: h[j+D]/x[j+D] still old
        float hd = (j + D < C) ? h[j + D] : th[j + D - C];
        float xd = (j + D < C) ? x[j + D] : tx[j + D - C];
        float hn = fmaf(wh0, h[j], wh1 * hd);
        float s  = fmaf(wx0, x[j], hn);
        s        = fmaf(wx1, xd, s);
        h[j] = hn;
        x[j] = fast_tanh(s);
    }
}

// ------------- Phase B: stride-64 interleave, slot k = element lane+64k -------------
// halo word: BASE + ((wv*2 + arr)*M + s)*64 + lane  (lane-contiguous, conflict-free)

// D = R (16 or 32): j+R -> lane (l+R)&63, slot k (+1 for high lanes).
template<int R, int BASE, int I>
__device__ __forceinline__ void layerBR(float (&hh)[C], float (&xx)[C],
        const float* wh, const float* wx, int lane, int wv, float* tb)
{
    const float wh0 = wh[2*I], wh1 = wh[2*I+1];
    const float wx0 = wx[2*I], wx1 = wx[2*I+1];
    const int nw = (wv + 1) & (NWV - 1);

    tb[BASE + (wv*2+0)*64 + lane] = hh[0];     // publish slot 0 (all lanes)
    tb[BASE + (wv*2+1)*64 + lane] = xx[0];
    __syncthreads();

    float fh[C + 1], fx[C + 1];
    #pragma unroll
    for (int k = 0; k < C; ++k) {
        fh[k] = __shfl(hh[k], (lane + R) & 63, 64);
        fx[k] = __shfl(xx[k], (lane + R) & 63, 64);
    }
    fh[C] = 0.0f; fx[C] = 0.0f;
    if (lane >= 64 - R) {                      // slot-16 = next wave's slot 0
        fh[C] = tb[BASE + (nw*2+0)*64 + (lane - (64 - R))];
        fx[C] = tb[BASE + (nw*2+1)*64 + (lane - (64 - R))];
    }
    const bool lo = lane < 64 - R;
    #pragma unroll
    for (int k = 0; k < C; ++k) {
        float hd = lo ? fh[k] : fh[k + 1];
        float xd = lo ? fx[k] : fx[k + 1];
        float hn = fmaf(wh0, hh[k], wh1 * hd);
        float s  = fmaf(wx0, xx[k], hn);
        s        = fmaf(wx1, xd, s);
        hh[k] = hn;
        xx[k] = fast_tanh(s);
    }
}

// D = 64*M (M in {1,2,4,8}): pure slot shift; only slots >= 16-M cross the wave.
template<int M, int BASE, bool PREBAR, int I>
__device__ __forceinline__ void layerBM(float (&hh)[C], float (&xx)[C],
        const float* wh, const float* wx, int lane, int wv, float* tb)
{
    const float wh0 = wh[2*I], wh1 = wh[2*I+1];
    const float wx0 = wx[2*I], wx1 = wx[2*I+1];
    const int nw = (wv + 1) & (NWV - 1);

    if constexpr (PREBAR) __syncthreads();     // M=8 overwrites both parity regions

    #pragma unroll
    for (int s = 0; s < M; ++s) {              // publish head slots
        tb[BASE + ((wv*2+0)*M + s)*64 + lane] = hh[s];
        tb[BASE + ((wv*2+1)*M + s)*64 + lane] = xx[s];
    }
    __syncthreads();

    float nh[M], nx[M];
    #pragma unroll
    for (int s = 0; s < M; ++s) {              // next wave's head slots
        nh[s] = tb[BASE + ((nw*2+0)*M + s)*64 + lane];
        nx[s] = tb[BASE + ((nw*2+1)*M + s)*64 + lane];
    }
    #pragma unroll
    for (int k = 0; k < C; ++k) {              // ascending k: hh[k+M] still old
        float hd = (k + M < C) ? hh[k + M] : nh[k + M - C];
        float xd = (k + M < C) ? xx[k + M] : nx[k + M - C];
        float hn = fmaf(wh0, hh[k], wh1 * hd);
        float s  = fmaf(wx0, xx[k], hn);
        s        = fmaf(wx1, xd, s);
        hh[k] = hn;
        xx[k] = fast_tanh(s);
    }
}

__global__ __launch_bounds__(NT, 2) void rawstack_ilv2(
    const float* __restrict__ hin, const float* __restrict__ xin,
    const float* __restrict__ wh,  const float* __restrict__ wx,
    float* __restrict__ out, int T, int Lout)
{
    __shared__ __align__(16) float tb[4096];   // 16 KB shared transpose/halo buffer
    __shared__ float hA[4][NWV][2][8];         // 1 KB phase-A head halos

    const int lane = threadIdx.x & 63;
    const int wv   = threadIdx.x >> 6;
    const int b    = blockIdx.y;
    const int W    = blockIdx.x * VALID;

    const float* hb = hin + (size_t)b * T;
    const float* xb = xin + (size_t)b * T;

    // ---- load contiguous chunks (clamped; garbage stays in invalid tail) ----
    float h[C], x[C];
    #pragma unroll
    for (int q = 0; q < C / 4; ++q) {
        int e = W + wv * 1024 + lane * C + q * 4;
        e = (e > T - 4) ? (T - 4) : e;
        const float4 hv = *(const float4*)(hb + e);
        const float4 xv = *(const float4*)(xb + e);
        h[q*4+0] = hv.x; h[q*4+1] = hv.y; h[q*4+2] = hv.z; h[q*4+3] = hv.w;
        x[q*4+0] = xv.x; x[q*4+1] = xv.y; x[q*4+2] = xv.z; x[q*4+3] = xv.w;
    }

    // ---- phase A: D = 1,2,4,8 ----
    layerA<1, 0>(h, x, wh, wx, lane, wv, hA);
    layerA<2, 1>(h, x, wh, wx, lane, wv, hA);
    layerA<4, 2>(h, x, wh, wx, lane, wv, hA);
    layerA<8, 3>(h, x, wh, wx, lane, wv, hA);

    // ---- transpose to stride-64 interleave, h then x through the SAME 16 KB ----
    float hh[C], xx[C];
    #pragma unroll
    for (int q = 0; q < C / 4; ++q) {
        const int w = tswz(wv * 1024 + lane * C + q * 4);
        *(float4*)&tb[w] = make_float4(h[q*4+0], h[q*4+1], h[q*4+2], h[q*4+3]);
    }
    __syncthreads();
    #pragma unroll
    for (int k = 0; k < C; ++k) hh[k] = tb[tswz(wv * 1024 + lane + 64 * k)];
    __syncthreads();                           // all h-reads done before x overwrites
    #pragma unroll
    for (int q = 0; q < C / 4; ++q) {
        const int w = tswz(wv * 1024 + lane * C + q * 4);
        *(float4*)&tb[w] = make_float4(x[q*4+0], x[q*4+1], x[q*4+2], x[q*4+3]);
    }
    __syncthreads();
    #pragma unroll
    for (int k = 0; k < C; ++k) xx[k] = tb[tswz(wv * 1024 + lane + 64 * k)];
    __syncthreads();                           // all x-reads done before halo publishes

    // ---- phase B: D = 16,32 (shuffle+select), D = 64..512 (slot shift) ----
    layerBR<16, P0B,        4>(hh, xx, wh, wx, lane, wv, tb);
    layerBR<32, P1B,        5>(hh, xx, wh, wx, lane, wv, tb);
    layerBM< 1, P0B, false, 6>(hh, xx, wh, wx, lane, wv, tb);   // D=64
    layerBM< 2, P1B, false, 7>(hh, xx, wh, wx, lane, wv, tb);   // D=128
    layerBM< 4, P0B, false, 8>(hh, xx, wh, wx, lane, wv, tb);   // D=256
    layerBM< 8, 0,   true,  9>(hh, xx, wh, wx, lane, wv, tb);   // D=512, full tb

    // ---- store (interleaved layout; waves 0..2 hold the 3072 valid outputs) ----
    if (wv < 3) {
        float* ob = out + (size_t)b * Lout;
        const int base = W + wv * 1024 + lane;
        #pragma unroll
        for (int k = 0; k < C; ++k) {
            const int col = base + 64 * k;
            if (col < Lout) ob[col] = xx[k];
        }
    }
}

extern "C" void kernel_launch(void* const* d_in, const int* in_sizes, int n_in,
                              void* d_out, int out_size, void* d_ws, size_t ws_size,
                              hipStream_t stream) {
    const float* h  = (const float*)d_in[0];
    const float* x  = (const float*)d_in[1];
    const float* wh = (const float*)d_in[2];
    const float* wx = (const float*)d_in[3];
    float* out = (float*)d_out;

    const int B    = 64;
    const int T    = in_sizes[0] / B;   // 131072
    const int Lout = out_size / B;      // 130049

    const int blocksPerRow = (Lout + VALID - 1) / VALID;   // 43

    dim3 grid(blocksPerRow, B);
    rawstack_ilv2<<<grid, NT, 0, stream>>>(h, x, wh, wx, out, T, Lout);
}